// Round 1
// baseline (4695.290 us; speedup 1.0000x reference)
//
#include <hip/hip_runtime.h>
#include <cstdint>

#define THREADS 256
#define BM 16
#define SEQL 256
#define IN_D 32
#define HID 64

// ws float offsets (prep kernel output)
#define OFF_IH0 0        // [32][64][4]  = 8192
#define OFF_HH0 8192     // [64][64][4]  = 16384
#define OFF_IH1 24576    // [64][64][4]  = 16384
#define OFF_HH1 40960    // [64][64][4]  = 16384
#define OFF_B0  57344    // [256] combined bih0+bhh0
#define OFF_B1  57600    // [256] combined bih1+bhh1
#define WS_FLOATS 57856

__device__ __forceinline__ float sigm(float v) {
  return __fdividef(1.f, 1.f + __expf(-v));
}
__device__ __forceinline__ float tanh_(float v) {
  float e = __expf(-2.f * fabsf(v));
  float r = __fdividef(1.f - e, 1.f + e);
  return copysignf(r, v);
}

// Repack weights to [j][k][gate] float4-friendly layout; combine biases.
__global__ __launch_bounds__(256) void prep_weights(
    const float* __restrict__ Wih0, const float* __restrict__ Whh0,
    const float* __restrict__ bih0, const float* __restrict__ bhh0,
    const float* __restrict__ Wih1, const float* __restrict__ Whh1,
    const float* __restrict__ bih1, const float* __restrict__ bhh1,
    float* __restrict__ ws) {
  int idx = blockIdx.x * blockDim.x + threadIdx.x;
  if (idx < 8192) {
    int g = idx & 3, k = (idx >> 2) & 63, d = idx >> 8;
    ws[OFF_IH0 + idx] = Wih0[(g * 64 + k) * 32 + d];
  } else if (idx < 24576) {
    int r = idx - 8192;
    int g = r & 3, k = (r >> 2) & 63, j = r >> 8;
    ws[OFF_HH0 + r] = Whh0[(g * 64 + k) * 64 + j];
  } else if (idx < 40960) {
    int r = idx - 24576;
    int g = r & 3, k = (r >> 2) & 63, j = r >> 8;
    ws[OFF_IH1 + r] = Wih1[(g * 64 + k) * 64 + j];
  } else if (idx < 57344) {
    int r = idx - 40960;
    int g = r & 3, k = (r >> 2) & 63, j = r >> 8;
    ws[OFF_HH1 + r] = Whh1[(g * 64 + k) * 64 + j];
  } else if (idx < 57600) {
    int r = idx - 57344;
    ws[OFF_B0 + r] = bih0[r] + bhh0[r];
  } else if (idx < WS_FLOATS) {
    int r = idx - 57600;
    ws[OFF_B1 + r] = bih1[r] + bhh1[r];
  }
}

// Software-pipelined K-loop: acc[b][gate] += sum_j h[b][j] * W[j][k][gate]
template <int NC>
__device__ __forceinline__ void kloop(const float4* __restrict__ w4, int k,
                                      const float* __restrict__ hbase, int hstride,
                                      int b0, float (&acc)[4][4]) {
  float4 wc[4], hc[4];
#pragma unroll
  for (int jj = 0; jj < 4; ++jj) wc[jj] = w4[jj * 64 + k];
#pragma unroll
  for (int i = 0; i < 4; ++i) hc[i] = *(const float4*)(hbase + (b0 + i) * hstride);
#pragma unroll 4
  for (int c = 0; c < NC; ++c) {
    float4 wn[4], hn[4];
    int jn = ((c + 1) & (NC - 1)) * 4;  // wrap: harmless redundant prefetch on last iter
#pragma unroll
    for (int jj = 0; jj < 4; ++jj) wn[jj] = w4[(jn + jj) * 64 + k];
#pragma unroll
    for (int i = 0; i < 4; ++i) hn[i] = *(const float4*)(hbase + (b0 + i) * hstride + jn);
#pragma unroll
    for (int i = 0; i < 4; ++i) {
      const float* hf = (const float*)&hc[i];
#pragma unroll
      for (int jj = 0; jj < 4; ++jj) {
        const float* wf = (const float*)&wc[jj];
        float hv = hf[jj];
        acc[i][0] = fmaf(hv, wf[0], acc[i][0]);
        acc[i][1] = fmaf(hv, wf[1], acc[i][1]);
        acc[i][2] = fmaf(hv, wf[2], acc[i][2]);
        acc[i][3] = fmaf(hv, wf[3], acc[i][3]);
      }
    }
#pragma unroll
    for (int jj = 0; jj < 4; ++jj) wc[jj] = wn[jj];
#pragma unroll
    for (int i = 0; i < 4; ++i) hc[i] = hn[i];
  }
}

__global__ __launch_bounds__(256) void lstm_fused(
    const float* __restrict__ x, const float* __restrict__ ws,
    const float* __restrict__ W1, const float* __restrict__ b1,
    const float* __restrict__ W2, const float* __restrict__ b2,
    float* __restrict__ out) {
  extern __shared__ __align__(16) float lds[];
  float* wih1 = lds;           // 16384 floats  [j][k][g]
  float* whh1 = lds + 16384;   // 16384 floats
  float* h1b  = lds + 32768;   // 2 x 1024  (double-buffered [b][k])
  float* h2b  = lds + 34816;   // 2 x 1024
  float* xb   = lds + 36864;   // 2 x 512   (double-buffered [b][d])

  const int tid = threadIdx.x;
  // Stage layer-1 weights global -> LDS (ih1 and hh1 are contiguous in ws)
  {
    const float4* gsrc = (const float4*)(ws + OFF_IH1);
    float4* ldst = (float4*)lds;
#pragma unroll
    for (int i = 0; i < 32; ++i) ldst[tid + i * 256] = gsrc[tid + i * 256];
  }
  // Zero initial h state buffers (cur = 0)
#pragma unroll
  for (int i = 0; i < 4; ++i) { h1b[tid + i * 256] = 0.f; h2b[tid + i * 256] = 0.f; }
  // Load x(t=0)
  const int bb = tid >> 4, d2 = (tid & 15) * 2;
  const float* xrow = x + (size_t)(blockIdx.x * BM + bb) * (SEQL * IN_D) + d2;
  *(float2*)(xb + bb * IN_D + d2) = *(const float2*)(xrow);
  __syncthreads();

  const int lane = tid & 63;
  const int k = (tid >> 6) * 16 + (lane & 15);  // per-wave disjoint k-sixteenth
  const int b0 = (lane >> 4) * 4;               // 4 local batch elements per thread
  float c1[4] = {0, 0, 0, 0}, c2[4] = {0, 0, 0, 0};
  float bias0[4], bias1[4];
#pragma unroll
  for (int g = 0; g < 4; ++g) {
    bias0[g] = ws[OFF_B0 + g * 64 + k];
    bias1[g] = ws[OFF_B1 + g * 64 + k];
  }
  const float4* wih0_4 = (const float4*)(ws + OFF_IH0);
  const float4* whh0_4 = (const float4*)(ws + OFF_HH0);
  const float4* wih1_4 = (const float4*)wih1;
  const float4* whh1_4 = (const float4*)whh1;

  int cur = 0;
  for (int t = 0; t < SEQL; ++t) {
    // ---- Phase A: layer 0 ----
    float acc[4][4];
#pragma unroll
    for (int i = 0; i < 4; ++i)
#pragma unroll
      for (int g = 0; g < 4; ++g) acc[i][g] = bias0[g];
    kloop<8>(wih0_4, k, xb + cur * 512, IN_D, b0, acc);
    kloop<16>(whh0_4, k, h1b + cur * 1024, HID, b0, acc);
    float* h1n = h1b + (cur ^ 1) * 1024;
#pragma unroll
    for (int i = 0; i < 4; ++i) {
      float gi = sigm(acc[i][0]), gf = sigm(acc[i][1]);
      float gg = tanh_(acc[i][2]), go = sigm(acc[i][3]);
      c1[i] = fmaf(gf, c1[i], gi * gg);
      h1n[(b0 + i) * HID + k] = go * tanh_(c1[i]);
    }
    __syncthreads();
    // ---- Phase B: layer 1 (+ x prefetch) ----
    float2 xpre;
    if (t < SEQL - 1) xpre = *(const float2*)(xrow + (t + 1) * IN_D);
#pragma unroll
    for (int i = 0; i < 4; ++i)
#pragma unroll
      for (int g = 0; g < 4; ++g) acc[i][g] = bias1[g];
    kloop<16>(wih1_4, k, h1b + (cur ^ 1) * 1024, HID, b0, acc);
    kloop<16>(whh1_4, k, h2b + cur * 1024, HID, b0, acc);
    float* h2n = h2b + (cur ^ 1) * 1024;
#pragma unroll
    for (int i = 0; i < 4; ++i) {
      float gi = sigm(acc[i][0]), gf = sigm(acc[i][1]);
      float gg = tanh_(acc[i][2]), go = sigm(acc[i][3]);
      c2[i] = fmaf(gf, c2[i], gi * gg);
      h2n[(b0 + i) * HID + k] = go * tanh_(c2[i]);
    }
    if (t < SEQL - 1) *(float2*)(xb + (cur ^ 1) * 512 + bb * IN_D + d2) = xpre;
    __syncthreads();
    cur ^= 1;
  }

  // ---- Head: f = relu(h2_last @ W1.T + b1); out = f @ W2.T + b2 ----
  // cur == 0 after 256 flips; final h2 is in h2b[cur].
  const int s = tid & 15, bo = tid >> 4;
  const float* h2row = h2b + cur * 1024 + bo * HID;
  float partial = 0.f;
#pragma unroll
  for (int kq = 0; kq < 4; ++kq) {
    int kk = s * 4 + kq;
    float f = b1[kk];
#pragma unroll
    for (int j = 0; j < 64; j += 4) {
      float4 w = *(const float4*)(W1 + kk * 64 + j);
      f = fmaf(w.x, h2row[j], f);
      f = fmaf(w.y, h2row[j + 1], f);
      f = fmaf(w.z, h2row[j + 2], f);
      f = fmaf(w.w, h2row[j + 3], f);
    }
    f = fmaxf(f, 0.f);
    partial = fmaf(f, W2[kk], partial);
  }
  partial += __shfl_xor(partial, 8, 64);
  partial += __shfl_xor(partial, 4, 64);
  partial += __shfl_xor(partial, 2, 64);
  partial += __shfl_xor(partial, 1, 64);
  if (s == 0) out[blockIdx.x * BM + bo] = partial + b2[0];
}

extern "C" void kernel_launch(void* const* d_in, const int* in_sizes, int n_in,
                              void* d_out, int out_size, void* d_ws, size_t ws_size,
                              hipStream_t stream) {
  const float* x    = (const float*)d_in[0];
  const float* Wih0 = (const float*)d_in[1];
  const float* Whh0 = (const float*)d_in[2];
  const float* bih0 = (const float*)d_in[3];
  const float* bhh0 = (const float*)d_in[4];
  const float* Wih1 = (const float*)d_in[5];
  const float* Whh1 = (const float*)d_in[6];
  const float* bih1 = (const float*)d_in[7];
  const float* bhh1 = (const float*)d_in[8];
  const float* W1   = (const float*)d_in[9];
  const float* b1   = (const float*)d_in[10];
  const float* W2   = (const float*)d_in[11];
  const float* b2   = (const float*)d_in[12];
  float* ws  = (float*)d_ws;
  float* out = (float*)d_out;

  prep_weights<<<WS_FLOATS / 256, 256, 0, stream>>>(Wih0, Whh0, bih0, bhh0,
                                                    Wih1, Whh1, bih1, bhh1, ws);

  const int lds_bytes = 37888 * 4;  // 151552 B < 160 KiB
  (void)hipFuncSetAttribute((const void*)lstm_fused,
                            hipFuncAttributeMaxDynamicSharedMemorySize, lds_bytes);
  lstm_fused<<<4096 / BM, THREADS, lds_bytes, stream>>>(x, ws, W1, b1, W2, b2, out);
}

// Round 2
// 887.664 us; speedup vs baseline: 5.2895x; 5.2895x over previous
//
#include <hip/hip_runtime.h>
#include <cstdint>

typedef __attribute__((ext_vector_type(8))) short s16x8;
typedef __attribute__((ext_vector_type(4))) float f32x4;
typedef __attribute__((ext_vector_type(2))) float f32x2;

#define SEQL 256

// ws byte offsets (prep output)
#define WS_B0H   0        // [3 kstep][16 ntile][64 lane][8] bf16 = 49152 B
#define WS_B0L   49152
#define WS_B1H   98304    // [4][16][64][8] bf16 = 65536 B (hi), then lo contiguous
#define WS_BIAS0 229376   // 256 f32, col-indexed (col = k*4+g)
#define WS_BIAS1 230400
#define WS_BYTES 231424

// LDS byte offsets
#define L_B1H 0           // 65536 hi + 65536 lo (staged contiguous from ws)
#define L_AH  131072      // 16 rows x 336 B (168 bf16/row: [x(32)|h1(64)|h2(64)]+pad)
#define L_AL  136448
#define L_G   141824      // 16 rows x 1040 B (260 f32/row) gate/exchange buffer
#define LDS_BYTES 158464
#define A_STRIDE 336
#define G_STRIDE 1040

__device__ __forceinline__ unsigned short f2bf(float f) {
  unsigned u = __float_as_uint(f);
  u += 0x7FFFu + ((u >> 16) & 1u);  // RNE
  return (unsigned short)(u >> 16);
}
__device__ __forceinline__ float bf2f(unsigned short h) {
  return __uint_as_float(((unsigned)h) << 16);
}
__device__ __forceinline__ float sigm(float v) {
  return __fdividef(1.f, 1.f + __expf(-v));
}
__device__ __forceinline__ float tanh_(float v) {
  float e = __expf(-2.f * fabsf(v));
  float r = __fdividef(1.f - e, 1.f + e);
  return copysignf(r, v);
}
__device__ __forceinline__ f32x4 mfma16(s16x8 a, s16x8 b, f32x4 c) {
  return __builtin_amdgcn_mfma_f32_16x16x32_bf16(a, b, c, 0, 0, 0);
}
__device__ __forceinline__ void split2(float a, float b, unsigned& hi, unsigned& lo) {
  unsigned short ha = f2bf(a), hb = f2bf(b);
  unsigned short la = f2bf(a - bf2f(ha)), lb = f2bf(b - bf2f(hb));
  hi = (unsigned)ha | ((unsigned)hb << 16);
  lo = (unsigned)la | ((unsigned)lb << 16);
}

// Pack weights into MFMA B-fragment order (B[k=quad*8+j][n=lane&15]), hi/lo
// bf16 split; gate column order col = k*4 + g. Combine biases per col.
__global__ __launch_bounds__(256) void prep(
    const float* __restrict__ Wih0, const float* __restrict__ Whh0,
    const float* __restrict__ bih0, const float* __restrict__ bhh0,
    const float* __restrict__ Wih1, const float* __restrict__ Whh1,
    const float* __restrict__ bih1, const float* __restrict__ bhh1,
    unsigned char* __restrict__ ws) {
  int e = blockIdx.x * 256 + threadIdx.x;
  if (e < 24576) {  // B0: K=96 = [x(32)|h1(64)], 3 ksteps
    int j = e & 7, lane = (e >> 3) & 63, nt = (e >> 9) & 15, ks = e >> 13;
    int kdim = ks * 32 + (lane >> 4) * 8 + j;
    int col = nt * 16 + (lane & 15);
    int ko = col >> 2, g = col & 3;
    float w = (kdim < 32) ? Wih0[(g * 64 + ko) * 32 + kdim]
                          : Whh0[(g * 64 + ko) * 64 + (kdim - 32)];
    unsigned short hi = f2bf(w);
    unsigned short lo = f2bf(w - bf2f(hi));
    ((unsigned short*)(ws + WS_B0H))[e] = hi;
    ((unsigned short*)(ws + WS_B0L))[e] = lo;
  } else if (e < 57344) {  // B1: K=128 = [h1(64)|h2(64)], 4 ksteps
    int r = e - 24576;
    int j = r & 7, lane = (r >> 3) & 63, nt = (r >> 9) & 15, ks = r >> 13;
    int kdim = ks * 32 + (lane >> 4) * 8 + j;
    int col = nt * 16 + (lane & 15);
    int ko = col >> 2, g = col & 3;
    float w = (kdim < 64) ? Wih1[(g * 64 + ko) * 64 + kdim]
                          : Whh1[(g * 64 + ko) * 64 + (kdim - 64)];
    unsigned short hi = f2bf(w);
    unsigned short lo = f2bf(w - bf2f(hi));
    ((unsigned short*)(ws + WS_B1H))[r] = hi;
    ((unsigned short*)(ws + WS_B1H + 65536))[r] = lo;
  } else if (e < 57856) {  // biases
    int r = e - 57344;
    int col = r & 255, ko = col >> 2, g = col & 3;
    float v = (r < 256) ? bih0[g * 64 + ko] + bhh0[g * 64 + ko]
                        : bih1[g * 64 + ko] + bhh1[g * 64 + ko];
    ((float*)(ws + (r < 256 ? WS_BIAS0 : WS_BIAS1)))[col] = v;
  }
}

__global__ __launch_bounds__(256, 1) void lstm_mfma(
    const float* __restrict__ x, const unsigned char* __restrict__ ws,
    const float* __restrict__ W1, const float* __restrict__ b1,
    const float* __restrict__ W2, const float* __restrict__ b2,
    float* __restrict__ out) {
  extern __shared__ __align__(16) unsigned char lds[];
  const int tid = threadIdx.x;
  const int lane = tid & 63, wave = tid >> 6;
  const int q = lane >> 4, mcol = lane & 15;

  // Stage B1 fragments (hi+lo, 131072 B contiguous) into LDS
  {
    const uint4* src = (const uint4*)(ws + WS_B1H);
    uint4* dst = (uint4*)(lds + L_B1H);
#pragma unroll
    for (int i = 0; i < 32; ++i) dst[tid + i * 256] = src[tid + i * 256];
  }
  // Zero A buffers (Ah+Al contiguous: 10752 B = 2688 words)
  {
    unsigned* a32 = (unsigned*)(lds + L_AH);
#pragma unroll
    for (int i = 0; i < 11; ++i) {
      int idx = tid + i * 256;
      if (idx < 2688) a32[idx] = 0;
    }
  }
  // Layer-0 B fragments: loop-invariant -> registers (96 VGPRs)
  s16x8 b0h[3][4], b0l[3][4];
#pragma unroll
  for (int ks = 0; ks < 3; ++ks)
#pragma unroll
    for (int tt = 0; tt < 4; ++tt) {
      int rec = (ks * 16 + wave * 4 + tt) * 64 + lane;
      b0h[ks][tt] = ((const s16x8*)(ws + WS_B0H))[rec];
      b0l[ks][tt] = ((const s16x8*)(ws + WS_B0L))[rec];
    }
  float bias0r[4], bias1r[4];
#pragma unroll
  for (int tt = 0; tt < 4; ++tt) {
    int col = wave * 64 + tt * 16 + mcol;
    bias0r[tt] = ((const float*)(ws + WS_BIAS0))[col];
    bias1r[tt] = ((const float*)(ws + WS_BIAS1))[col];
  }
  // x(0) -> A buffer (rows = batch, k-dims 0..31)
  const int bx = tid >> 4, d2 = (tid & 15) * 2;
  const float* xptr = x + (size_t)(blockIdx.x * 16 + bx) * (SEQL * 32) + d2;
  {
    f32x2 v = *(const f32x2*)(xptr);
    unsigned hi, lo;
    split2(v.x, v.y, hi, lo);
    *(unsigned*)(lds + L_AH + bx * A_STRIDE + d2 * 2) = hi;
    *(unsigned*)(lds + L_AL + bx * A_STRIDE + d2 * 2) = lo;
  }
  const int b = tid & 15, kq = tid >> 4;  // cell ownership: (b, k = kq*4+c)
  float c1s[4] = {0, 0, 0, 0}, c2s[4] = {0, 0, 0, 0}, h2fin[4] = {0, 0, 0, 0};
  __syncthreads();

  for (int t = 0; t < SEQL; ++t) {
    // ---- Phase A: G0 = [x|h1] @ B0 (+bias0), 3 ksteps x 3 split-products ----
    s16x8 ah[3], al[3];
#pragma unroll
    for (int ks = 0; ks < 3; ++ks) {
      int off = mcol * A_STRIDE + (ks * 32 + q * 8) * 2;
      ah[ks] = *(const s16x8*)(lds + L_AH + off);
      al[ks] = *(const s16x8*)(lds + L_AL + off);
    }
    f32x4 acc[4];
#pragma unroll
    for (int tt = 0; tt < 4; ++tt) {
      f32x4 a;
      a[0] = a[1] = a[2] = a[3] = bias0r[tt];
      acc[tt] = a;
    }
#pragma unroll
    for (int tt = 0; tt < 4; ++tt)
#pragma unroll
      for (int ks = 0; ks < 3; ++ks) {
        acc[tt] = mfma16(ah[ks], b0h[ks][tt], acc[tt]);
        acc[tt] = mfma16(al[ks], b0h[ks][tt], acc[tt]);
        acc[tt] = mfma16(ah[ks], b0l[ks][tt], acc[tt]);
      }
    // gates -> LDS (C layout: row = q*4+reg (batch), col = n)
#pragma unroll
    for (int tt = 0; tt < 4; ++tt)
#pragma unroll
      for (int r = 0; r < 4; ++r)
        *(float*)(lds + L_G + (q * 4 + r) * G_STRIDE +
                  (wave * 64 + tt * 16 + mcol) * 4) = acc[tt][r];
    __syncthreads();

    // ---- Cell 1 (+ x(t+1) prefetch into dead x region) ----
    f32x2 xv;
    if (t < SEQL - 1) xv = *(const f32x2*)(xptr + (t + 1) * 32);
    unsigned short hh[4], hl[4];
#pragma unroll
    for (int c = 0; c < 4; ++c) {
      f32x4 g4 = *(const f32x4*)(lds + L_G + b * G_STRIDE + kq * 64 + c * 16);
      float gi = sigm(g4[0]), gf = sigm(g4[1]);
      float gg = tanh_(g4[2]), go = sigm(g4[3]);
      c1s[c] = fmaf(gf, c1s[c], gi * gg);
      float h = go * tanh_(c1s[c]);
      hh[c] = f2bf(h);
      hl[c] = f2bf(h - bf2f(hh[c]));
    }
    {
      uint2 u;
      u.x = (unsigned)hh[0] | ((unsigned)hh[1] << 16);
      u.y = (unsigned)hh[2] | ((unsigned)hh[3] << 16);
      *(uint2*)(lds + L_AH + b * A_STRIDE + 64 + kq * 8) = u;  // h1 at kdim 32+k
      u.x = (unsigned)hl[0] | ((unsigned)hl[1] << 16);
      u.y = (unsigned)hl[2] | ((unsigned)hl[3] << 16);
      *(uint2*)(lds + L_AL + b * A_STRIDE + 64 + kq * 8) = u;
    }
    if (t < SEQL - 1) {
      unsigned hi, lo;
      split2(xv.x, xv.y, hi, lo);
      *(unsigned*)(lds + L_AH + bx * A_STRIDE + d2 * 2) = hi;
      *(unsigned*)(lds + L_AL + bx * A_STRIDE + d2 * 2) = lo;
    }
    __syncthreads();

    // ---- Phase B: G1 = [h1|h2] @ B1 (+bias1), 4 ksteps (A window base 32) ----
    s16x8 ah2[4], al2[4];
#pragma unroll
    for (int ks = 0; ks < 4; ++ks) {
      int off = mcol * A_STRIDE + (32 + ks * 32 + q * 8) * 2;
      ah2[ks] = *(const s16x8*)(lds + L_AH + off);
      al2[ks] = *(const s16x8*)(lds + L_AL + off);
    }
#pragma unroll
    for (int tt = 0; tt < 4; ++tt) {
      f32x4 a;
      a[0] = a[1] = a[2] = a[3] = bias1r[tt];
      acc[tt] = a;
    }
#pragma unroll
    for (int tt = 0; tt < 4; ++tt)
#pragma unroll
      for (int ks = 0; ks < 4; ++ks) {
        int rec = ((ks * 16 + wave * 4 + tt) * 64 + lane) * 16;
        s16x8 bh = *(const s16x8*)(lds + L_B1H + rec);
        s16x8 bl = *(const s16x8*)(lds + L_B1H + 65536 + rec);
        acc[tt] = mfma16(ah2[ks], bh, acc[tt]);
        acc[tt] = mfma16(al2[ks], bh, acc[tt]);
        acc[tt] = mfma16(ah2[ks], bl, acc[tt]);
      }
#pragma unroll
    for (int tt = 0; tt < 4; ++tt)
#pragma unroll
      for (int r = 0; r < 4; ++r)
        *(float*)(lds + L_G + (q * 4 + r) * G_STRIDE +
                  (wave * 64 + tt * 16 + mcol) * 4) = acc[tt][r];
    __syncthreads();

    // ---- Cell 2 ----
#pragma unroll
    for (int c = 0; c < 4; ++c) {
      f32x4 g4 = *(const f32x4*)(lds + L_G + b * G_STRIDE + kq * 64 + c * 16);
      float gi = sigm(g4[0]), gf = sigm(g4[1]);
      float gg = tanh_(g4[2]), go = sigm(g4[3]);
      c2s[c] = fmaf(gf, c2s[c], gi * gg);
      float h = go * tanh_(c2s[c]);
      h2fin[c] = h;
      hh[c] = f2bf(h);
      hl[c] = f2bf(h - bf2f(hh[c]));
    }
    {
      uint2 u;
      u.x = (unsigned)hh[0] | ((unsigned)hh[1] << 16);
      u.y = (unsigned)hh[2] | ((unsigned)hh[3] << 16);
      *(uint2*)(lds + L_AH + b * A_STRIDE + 192 + kq * 8) = u;  // h2 at kdim 96+k
      u.x = (unsigned)hl[0] | ((unsigned)hl[1] << 16);
      u.y = (unsigned)hl[2] | ((unsigned)hl[3] << 16);
      *(uint2*)(lds + L_AL + b * A_STRIDE + 192 + kq * 8) = u;
    }
    __syncthreads();
  }

  // ---- Head: f = relu(h2 @ W1.T + b1); out = f @ W2.T + b2 (fp32 h2) ----
#pragma unroll
  for (int c = 0; c < 4; ++c)
    *(float*)(lds + L_G + b * G_STRIDE + (kq * 4 + c) * 4) = h2fin[c];
  __syncthreads();
  const int s = tid & 15, bo = tid >> 4;
  const float* h2row = (const float*)(lds + L_G + bo * G_STRIDE);
  float partial = 0.f;
#pragma unroll
  for (int kk4 = 0; kk4 < 4; ++kk4) {
    int kk = s * 4 + kk4;
    float f = b1[kk];
#pragma unroll
    for (int j = 0; j < 64; j += 4) {
      f32x4 w = *(const f32x4*)(W1 + kk * 64 + j);
      f = fmaf(w[0], h2row[j], f);
      f = fmaf(w[1], h2row[j + 1], f);
      f = fmaf(w[2], h2row[j + 2], f);
      f = fmaf(w[3], h2row[j + 3], f);
    }
    f = fmaxf(f, 0.f);
    partial = fmaf(f, W2[kk], partial);
  }
  partial += __shfl_xor(partial, 8, 64);
  partial += __shfl_xor(partial, 4, 64);
  partial += __shfl_xor(partial, 2, 64);
  partial += __shfl_xor(partial, 1, 64);
  if (s == 0) out[blockIdx.x * 16 + bo] = partial + b2[0];
}

extern "C" void kernel_launch(void* const* d_in, const int* in_sizes, int n_in,
                              void* d_out, int out_size, void* d_ws, size_t ws_size,
                              hipStream_t stream) {
  const float* x    = (const float*)d_in[0];
  const float* Wih0 = (const float*)d_in[1];
  const float* Whh0 = (const float*)d_in[2];
  const float* bih0 = (const float*)d_in[3];
  const float* bhh0 = (const float*)d_in[4];
  const float* Wih1 = (const float*)d_in[5];
  const float* Whh1 = (const float*)d_in[6];
  const float* bih1 = (const float*)d_in[7];
  const float* bhh1 = (const float*)d_in[8];
  const float* W1   = (const float*)d_in[9];
  const float* b1   = (const float*)d_in[10];
  const float* W2   = (const float*)d_in[11];
  const float* b2   = (const float*)d_in[12];
  unsigned char* ws = (unsigned char*)d_ws;
  float* out = (float*)d_out;

  prep<<<(57856 + 255) / 256, 256, 0, stream>>>(Wih0, Whh0, bih0, bhh0,
                                                Wih1, Whh1, bih1, bhh1, ws);

  (void)hipFuncSetAttribute((const void*)lstm_mfma,
                            hipFuncAttributeMaxDynamicSharedMemorySize, LDS_BYTES);
  lstm_mfma<<<256, 256, LDS_BYTES, stream>>>(x, ws, W1, b1, W2, b2, out);
}

// Round 3
// 755.277 us; speedup vs baseline: 6.2166x; 1.1753x over previous
//
#include <hip/hip_runtime.h>
#include <cstdint>

typedef __attribute__((ext_vector_type(8))) short s16x8;
typedef __attribute__((ext_vector_type(4))) float f32x4;
typedef __attribute__((ext_vector_type(2))) float f32x2;

#define SEQL 256

// ws byte offsets (prep output)
#define WS_B0H   0        // [3 kstep][16 ntile][64 lane][8] bf16 = 49152 B
#define WS_B0L   49152
#define WS_B1H   98304    // [4][16][64][8] bf16 hi = 65536 B, then lo contiguous
#define WS_BIAS0 229376   // 256 f32, col-indexed (col = k*4+g)
#define WS_BIAS1 230400

// LDS byte offsets (static, 27392 B total -> 1 block/CU is LDS-unconstrained)
#define L_AH 0            // 16 rows x 336 B  (168 bf16/row: [x(32)|h1(64)|h2(64)]+pad)
#define L_AL 5376
#define L_G  10752        // 16 rows x 1040 B (260 f32/row) gate/exchange buffer
#define A_STRIDE 336
#define G_STRIDE 1040
#define LDS_TOTAL 27392

__device__ __forceinline__ unsigned short f2bf(float f) {
  unsigned u = __float_as_uint(f);
  u += 0x7FFFu + ((u >> 16) & 1u);  // RNE
  return (unsigned short)(u >> 16);
}
__device__ __forceinline__ float bf2f(unsigned short h) {
  return __uint_as_float(((unsigned)h) << 16);
}
__device__ __forceinline__ float sigm(float v) {
  return __fdividef(1.f, 1.f + __expf(-v));
}
__device__ __forceinline__ float tanh_(float v) {
  float e = __expf(-2.f * fabsf(v));
  float r = __fdividef(1.f - e, 1.f + e);
  return copysignf(r, v);
}
__device__ __forceinline__ f32x4 mfma16(s16x8 a, s16x8 b, f32x4 c) {
  return __builtin_amdgcn_mfma_f32_16x16x32_bf16(a, b, c, 0, 0, 0);
}
__device__ __forceinline__ s16x8 zero8() {
  s16x8 z;
#pragma unroll
  for (int i = 0; i < 8; ++i) z[i] = 0;
  return z;
}

// Pack weights into MFMA B-fragment order (B[k=quad*8+j][n=lane&15]), hi/lo
// bf16 split; gate column order col = k*4 + g. Combine biases per col.
// (unchanged from round 2 — validated)
__global__ __launch_bounds__(256) void prep(
    const float* __restrict__ Wih0, const float* __restrict__ Whh0,
    const float* __restrict__ bih0, const float* __restrict__ bhh0,
    const float* __restrict__ Wih1, const float* __restrict__ Whh1,
    const float* __restrict__ bih1, const float* __restrict__ bhh1,
    unsigned char* __restrict__ ws) {
  int e = blockIdx.x * 256 + threadIdx.x;
  if (e < 24576) {  // B0: K=96 = [x(32)|h1(64)], 3 ksteps
    int j = e & 7, lane = (e >> 3) & 63, nt = (e >> 9) & 15, ks = e >> 13;
    int kdim = ks * 32 + (lane >> 4) * 8 + j;
    int col = nt * 16 + (lane & 15);
    int ko = col >> 2, g = col & 3;
    float w = (kdim < 32) ? Wih0[(g * 64 + ko) * 32 + kdim]
                          : Whh0[(g * 64 + ko) * 64 + (kdim - 32)];
    unsigned short hi = f2bf(w);
    unsigned short lo = f2bf(w - bf2f(hi));
    ((unsigned short*)(ws + WS_B0H))[e] = hi;
    ((unsigned short*)(ws + WS_B0L))[e] = lo;
  } else if (e < 57344) {  // B1: K=128 = [h1(64)|h2(64)], 4 ksteps
    int r = e - 24576;
    int j = r & 7, lane = (r >> 3) & 63, nt = (r >> 9) & 15, ks = r >> 13;
    int kdim = ks * 32 + (lane >> 4) * 8 + j;
    int col = nt * 16 + (lane & 15);
    int ko = col >> 2, g = col & 3;
    float w = (kdim < 64) ? Wih1[(g * 64 + ko) * 64 + kdim]
                          : Whh1[(g * 64 + ko) * 64 + (kdim - 64)];
    unsigned short hi = f2bf(w);
    unsigned short lo = f2bf(w - bf2f(hi));
    ((unsigned short*)(ws + WS_B1H))[r] = hi;
    ((unsigned short*)(ws + WS_B1H + 65536))[r] = lo;
  } else if (e < 57856) {  // biases
    int r = e - 57344;
    int col = r & 255, ko = col >> 2, g = col & 3;
    float v = (r < 256) ? bih0[g * 64 + ko] + bhh0[g * 64 + ko]
                        : bih1[g * 64 + ko] + bhh1[g * 64 + ko];
    ((float*)(ws + (r < 256 ? WS_BIAS0 : WS_BIAS1)))[col] = v;
  }
}

__global__ __launch_bounds__(512, 2) void lstm_mfma2(
    const float* __restrict__ x, const unsigned char* __restrict__ ws,
    const float* __restrict__ W1, const float* __restrict__ b1,
    const float* __restrict__ W2, const float* __restrict__ b2,
    float* __restrict__ out) {
  __shared__ __align__(16) unsigned char lds[LDS_TOTAL];
  const int tid = threadIdx.x;
  const int lane = tid & 63, wave = tid >> 6;   // 8 waves
  const int q = lane >> 4, mcol = lane & 15;

  // ---- All weight fragments -> registers (loop-invariant) ----
  // wave owns 2 ntiles: nt = wave*2 + tt  (32 gate cols per wave)
  s16x8 b0h[3][2], b0l[3][2], b1h[4][2], b1l[4][2];
#pragma unroll
  for (int ks = 0; ks < 3; ++ks)
#pragma unroll
    for (int tt = 0; tt < 2; ++tt) {
      int rec = (ks * 16 + wave * 2 + tt) * 64 + lane;
      b0h[ks][tt] = ((const s16x8*)(ws + WS_B0H))[rec];
      b0l[ks][tt] = ((const s16x8*)(ws + WS_B0L))[rec];
    }
#pragma unroll
  for (int ks = 0; ks < 4; ++ks)
#pragma unroll
    for (int tt = 0; tt < 2; ++tt) {
      int rec = (ks * 16 + wave * 2 + tt) * 64 + lane;
      b1h[ks][tt] = ((const s16x8*)(ws + WS_B1H))[rec];
      b1l[ks][tt] = ((const s16x8*)(ws + WS_B1H + 65536))[rec];
    }
  float bias0r[2], bias1r[2];
#pragma unroll
  for (int tt = 0; tt < 2; ++tt) {
    int col = wave * 32 + tt * 16 + mcol;
    bias0r[tt] = ((const float*)(ws + WS_BIAS0))[col];
    bias1r[tt] = ((const float*)(ws + WS_BIAS1))[col];
  }

  // Zero A buffers (AH+AL contiguous: 10752 B = 2688 words)
  for (int i = tid; i < 2688; i += 512) ((unsigned*)(lds + L_AH))[i] = 0u;

  // x roles: thread -> (bx = tid>>5, d = tid&31), one float per step
  const int bx = tid >> 5, d = tid & 31;
  const float* xcol = x + (size_t)(blockIdx.x * 16 + bx) * (SEQL * 32) + d;
  {
    float v = xcol[0];
    unsigned short hi = f2bf(v), lo = f2bf(v - bf2f(hi));
    *(unsigned short*)(lds + L_AH + bx * A_STRIDE + d * 2) = hi;
    *(unsigned short*)(lds + L_AL + bx * A_STRIDE + d * 2) = lo;
  }
  // cell roles: thread -> (b = tid&15, k = 2*k2 + c), 2 cells per layer
  const int b = tid & 15, k2 = tid >> 4;
  float c1s[2] = {0, 0}, c2s[2] = {0, 0}, h2f[2] = {0, 0};
  // h1(t-1) fragments carried in registers across iterations (t=0: zeros)
  s16x8 ah1h[2], ah1l[2];
  ah1h[0] = ah1h[1] = ah1l[0] = ah1l[1] = zero8();
  __syncthreads();

#pragma unroll 1
  for (int t = 0; t < SEQL; ++t) {
    // issue next-x global load early; consumed in cell1
    float xnext = 0.f;
    if (t < SEQL - 1) xnext = xcol[(t + 1) * 32];

    // ---- Phase A: G0 = [x(t)|h1(t-1)] @ B0 (+bias0) ----
    s16x8 axh = *(const s16x8*)(lds + L_AH + mcol * A_STRIDE + q * 16);
    s16x8 axl = *(const s16x8*)(lds + L_AL + mcol * A_STRIDE + q * 16);
    f32x4 acc[2];
#pragma unroll
    for (int tt = 0; tt < 2; ++tt) {
      f32x4 a;
      a[0] = a[1] = a[2] = a[3] = bias0r[tt];
      acc[tt] = a;
    }
#pragma unroll
    for (int tt = 0; tt < 2; ++tt) {
      acc[tt] = mfma16(axh, b0h[0][tt], acc[tt]);
      acc[tt] = mfma16(axl, b0h[0][tt], acc[tt]);
      acc[tt] = mfma16(axh, b0l[0][tt], acc[tt]);
#pragma unroll
      for (int ks = 1; ks < 3; ++ks) {
        acc[tt] = mfma16(ah1h[ks - 1], b0h[ks][tt], acc[tt]);
        acc[tt] = mfma16(ah1l[ks - 1], b0h[ks][tt], acc[tt]);
        acc[tt] = mfma16(ah1h[ks - 1], b0l[ks][tt], acc[tt]);
      }
    }
#pragma unroll
    for (int tt = 0; tt < 2; ++tt)
#pragma unroll
      for (int r = 0; r < 4; ++r)
        *(float*)(lds + L_G + (q * 4 + r) * G_STRIDE +
                  (wave * 32 + tt * 16 + mcol) * 4) = acc[tt][r];
    __syncthreads();  // barrier 1

    // ---- Cell 1: h1(t), + x(t+1) into A (x(t) already consumed) ----
    unsigned short hh[2], hl[2];
#pragma unroll
    for (int c = 0; c < 2; ++c) {
      f32x4 g4 = *(const f32x4*)(lds + L_G + b * G_STRIDE + (k2 * 2 + c) * 16);
      float gi = sigm(g4[0]), gf = sigm(g4[1]);
      float gg = tanh_(g4[2]), go = sigm(g4[3]);
      c1s[c] = fmaf(gf, c1s[c], gi * gg);
      float h = go * tanh_(c1s[c]);
      hh[c] = f2bf(h);
      hl[c] = f2bf(h - bf2f(hh[c]));
    }
    *(unsigned*)(lds + L_AH + b * A_STRIDE + 64 + k2 * 4) =
        (unsigned)hh[0] | ((unsigned)hh[1] << 16);
    *(unsigned*)(lds + L_AL + b * A_STRIDE + 64 + k2 * 4) =
        (unsigned)hl[0] | ((unsigned)hl[1] << 16);
    if (t < SEQL - 1) {
      unsigned short xh = f2bf(xnext), xl = f2bf(xnext - bf2f(xh));
      *(unsigned short*)(lds + L_AH + bx * A_STRIDE + d * 2) = xh;
      *(unsigned short*)(lds + L_AL + bx * A_STRIDE + d * 2) = xl;
    }
    __syncthreads();  // barrier 2

    // ---- Phase B: G1 = [h1(t)|h2(t-1)] @ B1 (+bias1) ----
    s16x8 aBh[4], aBl[4];
#pragma unroll
    for (int ks = 0; ks < 4; ++ks) {
      int off = mcol * A_STRIDE + 64 + ks * 64 + q * 16;
      aBh[ks] = *(const s16x8*)(lds + L_AH + off);
      aBl[ks] = *(const s16x8*)(lds + L_AL + off);
    }
#pragma unroll
    for (int tt = 0; tt < 2; ++tt) {
      f32x4 a;
      a[0] = a[1] = a[2] = a[3] = bias1r[tt];
      acc[tt] = a;
    }
#pragma unroll
    for (int tt = 0; tt < 2; ++tt)
#pragma unroll
      for (int ks = 0; ks < 4; ++ks) {
        acc[tt] = mfma16(aBh[ks], b1h[ks][tt], acc[tt]);
        acc[tt] = mfma16(aBl[ks], b1h[ks][tt], acc[tt]);
        acc[tt] = mfma16(aBh[ks], b1l[ks][tt], acc[tt]);
      }
    // h1(t) fragments (B-window ks 0,1) feed next step's phase A (ks 1,2)
    ah1h[0] = aBh[0]; ah1h[1] = aBh[1];
    ah1l[0] = aBl[0]; ah1l[1] = aBl[1];
#pragma unroll
    for (int tt = 0; tt < 2; ++tt)
#pragma unroll
      for (int r = 0; r < 4; ++r)
        *(float*)(lds + L_G + (q * 4 + r) * G_STRIDE +
                  (wave * 32 + tt * 16 + mcol) * 4) = acc[tt][r];
    __syncthreads();  // barrier 3

    // ---- Cell 2: h2(t) ----  (no trailing barrier: next hazard is covered
    // by barrier 1 of t+1 — G1 not rewritten until after barrier 2 of t+1)
#pragma unroll
    for (int c = 0; c < 2; ++c) {
      f32x4 g4 = *(const f32x4*)(lds + L_G + b * G_STRIDE + (k2 * 2 + c) * 16);
      float gi = sigm(g4[0]), gf = sigm(g4[1]);
      float gg = tanh_(g4[2]), go = sigm(g4[3]);
      c2s[c] = fmaf(gf, c2s[c], gi * gg);
      float h = go * tanh_(c2s[c]);
      h2f[c] = h;
      hh[c] = f2bf(h);
      hl[c] = f2bf(h - bf2f(hh[c]));
    }
    *(unsigned*)(lds + L_AH + b * A_STRIDE + 192 + k2 * 4) =
        (unsigned)hh[0] | ((unsigned)hh[1] << 16);
    *(unsigned*)(lds + L_AL + b * A_STRIDE + 192 + k2 * 4) =
        (unsigned)hl[0] | ((unsigned)hl[1] << 16);
  }

  // ---- Head: f = relu(h2 @ W1.T + b1); out = f @ W2.T + b2 (fp32 h2) ----
  {
    f32x2 v;
    v[0] = h2f[0];
    v[1] = h2f[1];
    *(f32x2*)(lds + L_G + b * G_STRIDE + k2 * 8) = v;
  }
  __syncthreads();
  if (tid < 256) {
    const int s = tid & 15, bo = tid >> 4;
    const float* h2row = (const float*)(lds + L_G + bo * G_STRIDE);
    float partial = 0.f;
#pragma unroll
    for (int kk4 = 0; kk4 < 4; ++kk4) {
      int kk = s * 4 + kk4;
      float f = b1[kk];
#pragma unroll
      for (int j = 0; j < 64; j += 4) {
        f32x4 w = *(const f32x4*)(W1 + kk * 64 + j);
        f = fmaf(w[0], h2row[j], f);
        f = fmaf(w[1], h2row[j + 1], f);
        f = fmaf(w[2], h2row[j + 2], f);
        f = fmaf(w[3], h2row[j + 3], f);
      }
      f = fmaxf(f, 0.f);
      partial = fmaf(f, W2[kk], partial);
    }
    partial += __shfl_xor(partial, 8, 64);
    partial += __shfl_xor(partial, 4, 64);
    partial += __shfl_xor(partial, 2, 64);
    partial += __shfl_xor(partial, 1, 64);
    if (s == 0) out[blockIdx.x * 16 + bo] = partial + b2[0];
  }
}

extern "C" void kernel_launch(void* const* d_in, const int* in_sizes, int n_in,
                              void* d_out, int out_size, void* d_ws, size_t ws_size,
                              hipStream_t stream) {
  const float* x    = (const float*)d_in[0];
  const float* Wih0 = (const float*)d_in[1];
  const float* Whh0 = (const float*)d_in[2];
  const float* bih0 = (const float*)d_in[3];
  const float* bhh0 = (const float*)d_in[4];
  const float* Wih1 = (const float*)d_in[5];
  const float* Whh1 = (const float*)d_in[6];
  const float* bih1 = (const float*)d_in[7];
  const float* bhh1 = (const float*)d_in[8];
  const float* W1   = (const float*)d_in[9];
  const float* b1   = (const float*)d_in[10];
  const float* W2   = (const float*)d_in[11];
  const float* b2   = (const float*)d_in[12];
  unsigned char* ws = (unsigned char*)d_ws;
  float* out = (float*)d_out;

  prep<<<(57856 + 255) / 256, 256, 0, stream>>>(Wih0, Whh0, bih0, bhh0,
                                                Wih1, Whh1, bih1, bhh1, ws);
  lstm_mfma2<<<256, 512, 0, stream>>>(x, ws, W1, b1, W2, b2, out);
}

// Round 5
// 576.506 us; speedup vs baseline: 8.1444x; 1.3101x over previous
//
#include <hip/hip_runtime.h>
#include <cstdint>

typedef __attribute__((ext_vector_type(8))) short s16x8;
typedef __attribute__((ext_vector_type(4))) float f32x4;

#define SEQL 256

// ws byte offsets (prep output)
#define WS_B0H   0        // [3 kstep][16 ntile][64 lane][8] bf16 = 49152 B
#define WS_B0L   49152
#define WS_B1H   98304    // [4][16][64][8] bf16 hi = 65536 B, then lo contiguous
#define WS_BIAS0 229376   // 256 f32, col-indexed (col = k*4+g), pre-scaled
#define WS_BIAS1 230400

// LDS layout. A row = 264 bf16 elems (528 B; 132 words ≡ 4 mod 32 -> conflict-free)
// elem offsets in row: x_slot0@0, h1@32, h2_slot0@96, h2_slot1@160, x_slot1@224
#define ASTR 528
#define L_AH 0            // 16 x 528 = 8448
#define L_AL 8448
#define L_HD 16896        // head exchange: 16 rows x 272 B
#define HDSTR 272
#define LDS_TOTAL 21248

#define NEG_L   -1.4426950408889634f   // -log2(e)
#define NEG_2L  -2.8853900817779268f   // -2*log2(e)

__device__ __forceinline__ unsigned short f2bf(float f) {
  unsigned u = __float_as_uint(f);
  u += 0x7FFFu + ((u >> 16) & 1u);  // RNE
  return (unsigned short)(u >> 16);
}
__device__ __forceinline__ float bf2f(unsigned short h) {
  return __uint_as_float(((unsigned)h) << 16);
}
__device__ __forceinline__ float ex2(float x) { return __builtin_amdgcn_exp2f(x); }
__device__ __forceinline__ float rcp_(float x) { return __builtin_amdgcn_rcpf(x); }
// sigmoid(v) from pre-scaled vs = -log2e * v
__device__ __forceinline__ float sig_s(float vs) { return rcp_(1.f + ex2(vs)); }
// tanh(v) from pre-scaled vs = -2*log2e * v
__device__ __forceinline__ float tanh_s(float vs) {
  float e = ex2(-fabsf(vs));
  float r = (1.f - e) * rcp_(1.f + e);
  return copysignf(r, -vs);
}
// tanh(c), c unscaled
__device__ __forceinline__ float tanh_c(float c) {
  float e = ex2(fabsf(c) * NEG_2L);
  float r = (1.f - e) * rcp_(1.f + e);
  return copysignf(r, c);
}
__device__ __forceinline__ f32x4 mfma16(s16x8 a, s16x8 b, f32x4 c) {
  return __builtin_amdgcn_mfma_f32_16x16x32_bf16(a, b, c, 0, 0, 0);
}
__device__ __forceinline__ s16x8 zero8() {
  s16x8 z;
#pragma unroll
  for (int i = 0; i < 8; ++i) z[i] = 0;
  return z;
}
template <int PAT>
__device__ __forceinline__ int dppq(int v) {
  return __builtin_amdgcn_update_dpp(v, v, PAT, 0xf, 0xf, true);
}
// 4x4 transpose across the 4 lanes of a quad (lane bits [1:0]) x 4 regs.
// In: v[r] = M[row r][gate = lane&3]. Out: v[i] = M[row = lane&3][gate i].
__device__ __forceinline__ void quad_transpose(float (&v)[4], bool lodd, bool l2b) {
  int a0 = __float_as_int(v[0]), a1 = __float_as_int(v[1]);
  int a2 = __float_as_int(v[2]), a3 = __float_as_int(v[3]);
  // stage 1: exchange across lane bit0 (quad_perm [1,0,3,2] = 0xB1)
  int d0 = dppq<0xB1>(a0), d1 = dppq<0xB1>(a1);
  int d2 = dppq<0xB1>(a2), d3 = dppq<0xB1>(a3);
  int x0 = lodd ? d1 : a0;
  int x1 = lodd ? a1 : d0;
  int x2 = lodd ? d3 : a2;
  int x3 = lodd ? a3 : d2;
  // stage 2: exchange across lane bit1 (quad_perm [2,3,0,1] = 0x4E)
  int e0 = dppq<0x4E>(x0), e1 = dppq<0x4E>(x1);
  int e2 = dppq<0x4E>(x2), e3 = dppq<0x4E>(x3);
  v[0] = __int_as_float(l2b ? e2 : x0);
  v[1] = __int_as_float(l2b ? e3 : x1);
  v[2] = __int_as_float(l2b ? x2 : e0);
  v[3] = __int_as_float(l2b ? x3 : e1);
}

// Pack weights into MFMA B-fragment order, hi/lo bf16 split, PRE-SCALED by
// -log2e (gates i,f,o) / -2log2e (gate g) so activations use raw exp2.
__global__ __launch_bounds__(256) void prep(
    const float* __restrict__ Wih0, const float* __restrict__ Whh0,
    const float* __restrict__ bih0, const float* __restrict__ bhh0,
    const float* __restrict__ Wih1, const float* __restrict__ Whh1,
    const float* __restrict__ bih1, const float* __restrict__ bhh1,
    unsigned char* __restrict__ ws) {
  int e = blockIdx.x * 256 + threadIdx.x;
  if (e < 24576) {  // B0: K=96 = [x(32)|h1(64)], 3 ksteps
    int j = e & 7, lane = (e >> 3) & 63, nt = (e >> 9) & 15, ks = e >> 13;
    int kdim = ks * 32 + (lane >> 4) * 8 + j;
    int col = nt * 16 + (lane & 15);
    int ko = col >> 2, g = col & 3;
    float w = (kdim < 32) ? Wih0[(g * 64 + ko) * 32 + kdim]
                          : Whh0[(g * 64 + ko) * 64 + (kdim - 32)];
    w *= (g == 2) ? NEG_2L : NEG_L;
    unsigned short hi = f2bf(w);
    unsigned short lo = f2bf(w - bf2f(hi));
    ((unsigned short*)(ws + WS_B0H))[e] = hi;
    ((unsigned short*)(ws + WS_B0L))[e] = lo;
  } else if (e < 57344) {  // B1: K=128 = [h1(64)|h2(64)], 4 ksteps
    int r = e - 24576;
    int j = r & 7, lane = (r >> 3) & 63, nt = (r >> 9) & 15, ks = r >> 13;
    int kdim = ks * 32 + (lane >> 4) * 8 + j;
    int col = nt * 16 + (lane & 15);
    int ko = col >> 2, g = col & 3;
    float w = (kdim < 64) ? Wih1[(g * 64 + ko) * 64 + kdim]
                          : Whh1[(g * 64 + ko) * 64 + (kdim - 64)];
    w *= (g == 2) ? NEG_2L : NEG_L;
    unsigned short hi = f2bf(w);
    unsigned short lo = f2bf(w - bf2f(hi));
    ((unsigned short*)(ws + WS_B1H))[r] = hi;
    ((unsigned short*)(ws + WS_B1H + 65536))[r] = lo;
  } else if (e < 57856) {  // biases (pre-scaled)
    int r = e - 57344;
    int col = r & 255, ko = col >> 2, g = col & 3;
    float v = (r < 256) ? bih0[g * 64 + ko] + bhh0[g * 64 + ko]
                        : bih1[g * 64 + ko] + bhh1[g * 64 + ko];
    v *= (g == 2) ? NEG_2L : NEG_L;
    ((float*)(ws + (r < 256 ? WS_BIAS0 : WS_BIAS1)))[col] = v;
  }
}

__global__ __launch_bounds__(512, 2) void lstm_mfma3(
    const float* __restrict__ x, const unsigned char* __restrict__ ws,
    const float* __restrict__ W1, const float* __restrict__ b1,
    const float* __restrict__ W2, const float* __restrict__ b2,
    float* __restrict__ out) {
  __shared__ __align__(16) unsigned char lds[LDS_TOTAL];
  const int tid = threadIdx.x;
  const int lane = tid & 63, wave = tid >> 6;  // 8 waves
  const int q = lane >> 4, mcol = lane & 15;
  const bool lodd = (lane & 1) != 0, l2b = (lane & 2) != 0;

  // ---- All weight fragments -> registers (loop-invariant) ----
  s16x8 b0h[3][2], b0l[3][2], b1h[4][2], b1l[4][2];
#pragma unroll
  for (int ks = 0; ks < 3; ++ks)
#pragma unroll
    for (int tt = 0; tt < 2; ++tt) {
      int rec = (ks * 16 + wave * 2 + tt) * 64 + lane;
      b0h[ks][tt] = ((const s16x8*)(ws + WS_B0H))[rec];
      b0l[ks][tt] = ((const s16x8*)(ws + WS_B0L))[rec];
    }
#pragma unroll
  for (int ks = 0; ks < 4; ++ks)
#pragma unroll
    for (int tt = 0; tt < 2; ++tt) {
      int rec = (ks * 16 + wave * 2 + tt) * 64 + lane;
      b1h[ks][tt] = ((const s16x8*)(ws + WS_B1H))[rec];
      b1l[ks][tt] = ((const s16x8*)(ws + WS_B1H + 65536))[rec];
    }
  float bias0r[2], bias1r[2];
#pragma unroll
  for (int tt = 0; tt < 2; ++tt) {
    int col = wave * 32 + tt * 16 + mcol;
    bias0r[tt] = ((const float*)(ws + WS_BIAS0))[col];
    bias1r[tt] = ((const float*)(ws + WS_BIAS1))[col];
  }

  // Zero A buffers (AH+AL contiguous: 16896 B = 4224 words)
  for (int i = tid; i < 4224; i += 512) ((unsigned*)(lds + L_AH))[i] = 0u;

  // x staging role: thread -> (bx = tid>>5, d = tid&31)
  const int bx = tid >> 5, d = tid & 31;
  const float* xcol = x + (size_t)(blockIdx.x * 16 + bx) * (SEQL * 32) + d;
  {
    float v = xcol[0];  // x(0) -> slot 0
    unsigned short hi = f2bf(v), lo = f2bf(v - bf2f(hi));
    *(unsigned short*)(lds + L_AH + bx * ASTR + d * 2) = hi;
    *(unsigned short*)(lds + L_AL + bx * ASTR + d * 2) = lo;
  }
  // cell role: per tt one cell (b = q*4+(lane&3), k = wave*8+tt*4+(mcol>>2))
  const int brow = q * 4 + (lane & 3);
  const int kc0 = wave * 8 + (mcol >> 2), kc1 = kc0 + 4;
  float c1s[2] = {0, 0}, c2s[2] = {0, 0}, h2f[2] = {0, 0};
  s16x8 ah1h[2], ah1l[2];  // h1(t-1) fragments carried in regs
  ah1h[0] = ah1h[1] = ah1l[0] = ah1l[1] = zero8();
  __syncthreads();

#pragma unroll 1
  for (int t = 0; t < SEQL; ++t) {
    const int par = t & 1;
    const int xrd = par ? 448 : 0, xwr = par ? 0 : 448;      // byte offs in row
    const int h2rd = par ? 320 : 192, h2wr = par ? 192 : 320;

    float xnext = 0.f;
    if (t < SEQL - 1) xnext = xcol[(t + 1) * 32];

    // ---- Phase A: G0 = [x(t)|h1(t-1)] @ B0 (+bias0) ----
    s16x8 axh = *(const s16x8*)(lds + L_AH + mcol * ASTR + xrd + q * 16);
    s16x8 axl = *(const s16x8*)(lds + L_AL + mcol * ASTR + xrd + q * 16);
    f32x4 acc[2];
#pragma unroll
    for (int tt = 0; tt < 2; ++tt) {
      f32x4 a;
      a[0] = a[1] = a[2] = a[3] = bias0r[tt];
      acc[tt] = a;
    }
#pragma unroll
    for (int tt = 0; tt < 2; ++tt) {
      acc[tt] = mfma16(axh, b0h[0][tt], acc[tt]);
      acc[tt] = mfma16(axl, b0h[0][tt], acc[tt]);
      acc[tt] = mfma16(axh, b0l[0][tt], acc[tt]);
#pragma unroll
      for (int ks = 1; ks < 3; ++ks) {
        acc[tt] = mfma16(ah1h[ks - 1], b0h[ks][tt], acc[tt]);
        acc[tt] = mfma16(ah1l[ks - 1], b0h[ks][tt], acc[tt]);
        acc[tt] = mfma16(ah1h[ks - 1], b0l[ks][tt], acc[tt]);
      }
    }
    // ---- Cell 1 in-register (DPP transpose), write h1 + x(t+1) ----
#pragma unroll
    for (int tt = 0; tt < 2; ++tt) {
      float g4[4] = {acc[tt][0], acc[tt][1], acc[tt][2], acc[tt][3]};
      quad_transpose(g4, lodd, l2b);
      float gi = sig_s(g4[0]), gf = sig_s(g4[1]);
      float gg = tanh_s(g4[2]), go = sig_s(g4[3]);
      c1s[tt] = fmaf(gf, c1s[tt], gi * gg);
      float h = go * tanh_c(c1s[tt]);
      unsigned short hh = f2bf(h);
      int off = brow * ASTR + 64 + (tt ? kc1 : kc0) * 2;
      *(unsigned short*)(lds + L_AH + off) = hh;
      *(unsigned short*)(lds + L_AL + off) = f2bf(h - bf2f(hh));
    }
    if (t < SEQL - 1) {
      unsigned short xh = f2bf(xnext), xl = f2bf(xnext - bf2f(xh));
      *(unsigned short*)(lds + L_AH + bx * ASTR + xwr + d * 2) = xh;
      *(unsigned short*)(lds + L_AL + bx * ASTR + xwr + d * 2) = xl;
    }
    __syncthreads();  // barrier 1: h1(t) visible; x(t+1) staged

    // ---- Phase B: G1 = [h1(t)|h2(t-1)] @ B1 (+bias1) ----
    s16x8 aBh[4], aBl[4];
#pragma unroll
    for (int ks = 0; ks < 2; ++ks) {
      int off = mcol * ASTR + 64 + ks * 64 + q * 16;
      aBh[ks] = *(const s16x8*)(lds + L_AH + off);
      aBl[ks] = *(const s16x8*)(lds + L_AL + off);
    }
#pragma unroll
    for (int ks = 2; ks < 4; ++ks) {
      int off = mcol * ASTR + h2rd + (ks - 2) * 64 + q * 16;
      aBh[ks] = *(const s16x8*)(lds + L_AH + off);
      aBl[ks] = *(const s16x8*)(lds + L_AL + off);
    }
#pragma unroll
    for (int tt = 0; tt < 2; ++tt) {
      f32x4 a;
      a[0] = a[1] = a[2] = a[3] = bias1r[tt];
      acc[tt] = a;
    }
#pragma unroll
    for (int tt = 0; tt < 2; ++tt)
#pragma unroll
      for (int ks = 0; ks < 4; ++ks) {
        acc[tt] = mfma16(aBh[ks], b1h[ks][tt], acc[tt]);
        acc[tt] = mfma16(aBl[ks], b1h[ks][tt], acc[tt]);
        acc[tt] = mfma16(aBh[ks], b1l[ks][tt], acc[tt]);
      }
    ah1h[0] = aBh[0]; ah1h[1] = aBh[1];  // h1(t) feeds next phase A
    ah1l[0] = aBl[0]; ah1l[1] = aBl[1];
    // ---- Cell 2 in-register, write h2 into parity slot ----
#pragma unroll
    for (int tt = 0; tt < 2; ++tt) {
      float g4[4] = {acc[tt][0], acc[tt][1], acc[tt][2], acc[tt][3]};
      quad_transpose(g4, lodd, l2b);
      float gi = sig_s(g4[0]), gf = sig_s(g4[1]);
      float gg = tanh_s(g4[2]), go = sig_s(g4[3]);
      c2s[tt] = fmaf(gf, c2s[tt], gi * gg);
      float h = go * tanh_c(c2s[tt]);
      h2f[tt] = h;
      unsigned short hh = f2bf(h);
      int off = brow * ASTR + h2wr + (tt ? kc1 : kc0) * 2;
      *(unsigned short*)(lds + L_AH + off) = hh;
      *(unsigned short*)(lds + L_AL + off) = f2bf(h - bf2f(hh));
    }
    __syncthreads();  // barrier 2: h2(t) visible; phase-B reads of t done
  }

  // ---- Head: f = relu(h2 @ W1.T + b1); out = f @ W2.T + b2 ----
  *(float*)(lds + L_HD + brow * HDSTR + kc0 * 4) = h2f[0];
  *(float*)(lds + L_HD + brow * HDSTR + kc1 * 4) = h2f[1];
  __syncthreads();
  if (tid < 256) {
    const int s = tid & 15, bo = tid >> 4;
    const float* h2row = (const float*)(lds + L_HD + bo * HDSTR);
    float partial = 0.f;
#pragma unroll
    for (int kk4 = 0; kk4 < 4; ++kk4) {
      int kk = s * 4 + kk4;
      float f = b1[kk];
#pragma unroll
      for (int j = 0; j < 64; j += 4) {
        f32x4 w = *(const f32x4*)(W1 + kk * 64 + j);
        f = fmaf(w[0], h2row[j], f);
        f = fmaf(w[1], h2row[j + 1], f);
        f = fmaf(w[2], h2row[j + 2], f);
        f = fmaf(w[3], h2row[j + 3], f);
      }
      f = fmaxf(f, 0.f);
      partial = fmaf(f, W2[kk], partial);
    }
    partial += __shfl_xor(partial, 8, 64);
    partial += __shfl_xor(partial, 4, 64);
    partial += __shfl_xor(partial, 2, 64);
    partial += __shfl_xor(partial, 1, 64);
    if (s == 0) out[blockIdx.x * 16 + bo] = partial + b2[0];
  }
}

extern "C" void kernel_launch(void* const* d_in, const int* in_sizes, int n_in,
                              void* d_out, int out_size, void* d_ws, size_t ws_size,
                              hipStream_t stream) {
  const float* x    = (const float*)d_in[0];
  const float* Wih0 = (const float*)d_in[1];
  const float* Whh0 = (const float*)d_in[2];
  const float* bih0 = (const float*)d_in[3];
  const float* bhh0 = (const float*)d_in[4];
  const float* Wih1 = (const float*)d_in[5];
  const float* Whh1 = (const float*)d_in[6];
  const float* bih1 = (const float*)d_in[7];
  const float* bhh1 = (const float*)d_in[8];
  const float* W1   = (const float*)d_in[9];
  const float* b1   = (const float*)d_in[10];
  const float* W2   = (const float*)d_in[11];
  const float* b2   = (const float*)d_in[12];
  unsigned char* ws = (unsigned char*)d_ws;
  float* out = (float*)d_out;

  prep<<<(57856 + 255) / 256, 256, 0, stream>>>(Wih0, Whh0, bih0, bhh0,
                                                Wih1, Whh1, bih1, bhh1, ws);
  lstm_mfma3<<<256, 512, 0, stream>>>(x, ws, W1, b1, W2, b2, out);
}

// Round 6
// 523.638 us; speedup vs baseline: 8.9667x; 1.1010x over previous
//
#include <hip/hip_runtime.h>
#include <cstdint>

typedef __attribute__((ext_vector_type(8))) short s16x8;
typedef __attribute__((ext_vector_type(4))) float f32x4;

#define SEQL 256

// ws byte offsets (prep output)
#define WS_B0H   0        // [3 kstep][16 ntile][64 lane][8] bf16 = 49152 B
#define WS_B0L   49152
#define WS_B1H   98304    // [4][16][64][8] bf16 hi = 65536 B, then lo contiguous
#define WS_BIAS0 229376   // 256 f32, col-indexed (col = k*4+g), pre-scaled
#define WS_BIAS1 230400

// LDS: A row = 328 bf16 elems (656 B = 164 words ≡ 4 mod 32).
// byte offs in row: x0@0(64B) x1@64 h1_0@128(128B) h1_1@256 h2_0@384 h2_1@512 pad@640
#define ASTR 656
#define L_AH 0            // 16 x 656 = 10496
#define L_AL 10496
#define L_HD 20992        // head exchange: 16 rows x 272 B
#define HDSTR 272
#define LDS_TOTAL 25344

#define NEG_L   -1.4426950408889634f   // -log2(e)
#define NEG_2L  -2.8853900817779268f   // -2*log2(e)

__device__ __forceinline__ unsigned short f2bf(float f) {
  unsigned u = __float_as_uint(f);
  u += 0x7FFFu + ((u >> 16) & 1u);  // RNE
  return (unsigned short)(u >> 16);
}
__device__ __forceinline__ float bf2f(unsigned short h) {
  return __uint_as_float(((unsigned)h) << 16);
}
__device__ __forceinline__ float ex2(float x) { return __builtin_amdgcn_exp2f(x); }
__device__ __forceinline__ float rcp_(float x) { return __builtin_amdgcn_rcpf(x); }
__device__ __forceinline__ float sig_s(float vs) { return rcp_(1.f + ex2(vs)); }
__device__ __forceinline__ float tanh_s(float vs) {
  float e = ex2(-fabsf(vs));
  float r = (1.f - e) * rcp_(1.f + e);
  return copysignf(r, -vs);
}
__device__ __forceinline__ float tanh_c(float c) {
  float e = ex2(fabsf(c) * NEG_2L);
  float r = (1.f - e) * rcp_(1.f + e);
  return copysignf(r, c);
}
__device__ __forceinline__ f32x4 mfma16(s16x8 a, s16x8 b, f32x4 c) {
  return __builtin_amdgcn_mfma_f32_16x16x32_bf16(a, b, c, 0, 0, 0);
}
__device__ __forceinline__ s16x8 zero8() {
  s16x8 z;
#pragma unroll
  for (int i = 0; i < 8; ++i) z[i] = 0;
  return z;
}
template <int PAT>
__device__ __forceinline__ int dppq(int v) {
  return __builtin_amdgcn_update_dpp(v, v, PAT, 0xf, 0xf, true);
}
// 4x4 transpose across quad lanes x 4 regs. In: v[r]=M[row r][lane&3].
// Out: v[i]=M[lane&3][i].
__device__ __forceinline__ void quad_transpose(float (&v)[4], bool lodd, bool l2b) {
  int a0 = __float_as_int(v[0]), a1 = __float_as_int(v[1]);
  int a2 = __float_as_int(v[2]), a3 = __float_as_int(v[3]);
  int d0 = dppq<0xB1>(a0), d1 = dppq<0xB1>(a1);
  int d2 = dppq<0xB1>(a2), d3 = dppq<0xB1>(a3);
  int x0 = lodd ? d1 : a0;
  int x1 = lodd ? a1 : d0;
  int x2 = lodd ? d3 : a2;
  int x3 = lodd ? a3 : d2;
  int e0 = dppq<0x4E>(x0), e1 = dppq<0x4E>(x1);
  int e2 = dppq<0x4E>(x2), e3 = dppq<0x4E>(x3);
  v[0] = __int_as_float(l2b ? e2 : x0);
  v[1] = __int_as_float(l2b ? e3 : x1);
  v[2] = __int_as_float(l2b ? x2 : e0);
  v[3] = __int_as_float(l2b ? x3 : e1);
}

// Pack weights into MFMA B-fragment order, hi/lo bf16 split, pre-scaled by
// -log2e (i,f,o) / -2log2e (g). (unchanged — validated rounds 2-5)
__global__ __launch_bounds__(256) void prep(
    const float* __restrict__ Wih0, const float* __restrict__ Whh0,
    const float* __restrict__ bih0, const float* __restrict__ bhh0,
    const float* __restrict__ Wih1, const float* __restrict__ Whh1,
    const float* __restrict__ bih1, const float* __restrict__ bhh1,
    unsigned char* __restrict__ ws) {
  int e = blockIdx.x * 256 + threadIdx.x;
  if (e < 24576) {  // B0: K=96 = [x(32)|h1(64)]
    int j = e & 7, lane = (e >> 3) & 63, nt = (e >> 9) & 15, ks = e >> 13;
    int kdim = ks * 32 + (lane >> 4) * 8 + j;
    int col = nt * 16 + (lane & 15);
    int ko = col >> 2, g = col & 3;
    float w = (kdim < 32) ? Wih0[(g * 64 + ko) * 32 + kdim]
                          : Whh0[(g * 64 + ko) * 64 + (kdim - 32)];
    w *= (g == 2) ? NEG_2L : NEG_L;
    unsigned short hi = f2bf(w);
    unsigned short lo = f2bf(w - bf2f(hi));
    ((unsigned short*)(ws + WS_B0H))[e] = hi;
    ((unsigned short*)(ws + WS_B0L))[e] = lo;
  } else if (e < 57344) {  // B1: K=128 = [h1(64)|h2(64)]
    int r = e - 24576;
    int j = r & 7, lane = (r >> 3) & 63, nt = (r >> 9) & 15, ks = r >> 13;
    int kdim = ks * 32 + (lane >> 4) * 8 + j;
    int col = nt * 16 + (lane & 15);
    int ko = col >> 2, g = col & 3;
    float w = (kdim < 64) ? Wih1[(g * 64 + ko) * 64 + kdim]
                          : Whh1[(g * 64 + ko) * 64 + (kdim - 64)];
    w *= (g == 2) ? NEG_2L : NEG_L;
    unsigned short hi = f2bf(w);
    unsigned short lo = f2bf(w - bf2f(hi));
    ((unsigned short*)(ws + WS_B1H))[r] = hi;
    ((unsigned short*)(ws + WS_B1H + 65536))[r] = lo;
  } else if (e < 57856) {  // biases (pre-scaled)
    int r = e - 57344;
    int col = r & 255, ko = col >> 2, g = col & 3;
    float v = (r < 256) ? bih0[g * 64 + ko] + bhh0[g * 64 + ko]
                        : bih1[g * 64 + ko] + bhh1[g * 64 + ko];
    v *= (g == 2) ? NEG_2L : NEG_L;
    ((float*)(ws + (r < 256 ? WS_BIAS0 : WS_BIAS1)))[col] = v;
  }
}

__global__ __launch_bounds__(1024, 4) void lstm_mfma4(
    const float* __restrict__ x, const unsigned char* __restrict__ ws,
    const float* __restrict__ W1, const float* __restrict__ b1,
    const float* __restrict__ W2, const float* __restrict__ b2,
    float* __restrict__ out) {
  __shared__ __align__(16) unsigned char lds[LDS_TOTAL];
  const int tid = threadIdx.x;
  const int lane = tid & 63, wave = tid >> 6;  // 16 waves, 1 ntile each
  const int q = lane >> 4, mcol = lane & 15;
  const bool lodd = (lane & 1) != 0, l2b = (lane & 2) != 0;

  // ---- Weight fragments -> registers (loop-invariant, 1 ntile/wave) ----
  s16x8 b0h[3], b0l[3], b1h[4], b1l[4];
#pragma unroll
  for (int ks = 0; ks < 3; ++ks) {
    int rec = (ks * 16 + wave) * 64 + lane;
    b0h[ks] = ((const s16x8*)(ws + WS_B0H))[rec];
    b0l[ks] = ((const s16x8*)(ws + WS_B0L))[rec];
  }
#pragma unroll
  for (int ks = 0; ks < 4; ++ks) {
    int rec = (ks * 16 + wave) * 64 + lane;
    b1h[ks] = ((const s16x8*)(ws + WS_B1H))[rec];
    b1l[ks] = ((const s16x8*)(ws + WS_B1H + 65536))[rec];
  }
  const int col = wave * 16 + mcol;
  const float bias0r = ((const float*)(ws + WS_BIAS0))[col];
  const float bias1r = ((const float*)(ws + WS_BIAS1))[col];

  // Zero A buffers (AH+AL contiguous: 20992 B = 5248 words)
  for (int i = tid; i < 5248; i += 1024) ((unsigned*)(lds + L_AH))[i] = 0u;

  // x staging role (threads 0..511): bx = tid>>5 (0..15), d = tid&31
  const bool do_x = tid < 512;
  const int bx = tid >> 5, d = tid & 31;
  const float* xcol = x + (size_t)(blockIdx.x * 16 + (do_x ? bx : 0)) * (SEQL * 32) + d;
  if (do_x) {
    float v = xcol[0];  // x(0) -> slot 0
    unsigned short hi = f2bf(v), lo = f2bf(v - bf2f(hi));
    *(unsigned short*)(lds + L_AH + bx * ASTR + d * 2) = hi;
    *(unsigned short*)(lds + L_AL + bx * ASTR + d * 2) = lo;
  }
  // cell role: 1 cell/layer: (brow = q*4+(lane&3), kc = wave*4+(mcol>>2))
  const int brow = q * 4 + (lane & 3);
  const int kc = wave * 4 + (mcol >> 2);
  float c1 = 0.f, c2 = 0.f, h2f = 0.f;
  s16x8 ah1h[2], ah1l[2];  // h1(t-1) A-fragments carried in registers
  ah1h[0] = ah1h[1] = ah1l[0] = ah1l[1] = zero8();
  __syncthreads();

  auto step = [&](int t, const int par) {
    const int xrd = par * 64, xwr = (par ^ 1) * 64;
    const int h1s = 128 + par * 128;          // h1(t) slot
    const int h2rd = 384 + (par ^ 1) * 128;   // h2(t-1)
    const int h2wr = 384 + par * 128;         // h2(t)

    float xnext = 0.f;
    if (do_x && t < SEQL - 1) xnext = xcol[(t + 1) * 32];

    // ---- Phase A: G0 = [x(t)|h1(t-1)] @ B0 ----
    s16x8 axh = *(const s16x8*)(lds + L_AH + mcol * ASTR + xrd + q * 16);
    s16x8 axl = *(const s16x8*)(lds + L_AL + mcol * ASTR + xrd + q * 16);
    f32x4 acc;
    acc[0] = acc[1] = acc[2] = acc[3] = bias0r;
    acc = mfma16(axh, b0h[0], acc);
    acc = mfma16(axl, b0h[0], acc);
    acc = mfma16(axh, b0l[0], acc);
#pragma unroll
    for (int ks = 0; ks < 2; ++ks) {
      acc = mfma16(ah1h[ks], b0h[ks + 1], acc);
      acc = mfma16(ah1l[ks], b0h[ks + 1], acc);
      acc = mfma16(ah1h[ks], b0l[ks + 1], acc);
    }
    // ---- Cell 1 (in-register gate transpose) ----
    {
      float g4[4] = {acc[0], acc[1], acc[2], acc[3]};
      quad_transpose(g4, lodd, l2b);
      float gi = sig_s(g4[0]), gf = sig_s(g4[1]);
      float gg = tanh_s(g4[2]), go = sig_s(g4[3]);
      c1 = fmaf(gf, c1, gi * gg);
      float h = go * tanh_c(c1);
      unsigned short hh = f2bf(h);
      int off = brow * ASTR + h1s + kc * 2;
      *(unsigned short*)(lds + L_AH + off) = hh;
      *(unsigned short*)(lds + L_AL + off) = f2bf(h - bf2f(hh));
    }
    if (do_x && t < SEQL - 1) {
      unsigned short xh = f2bf(xnext), xl = f2bf(xnext - bf2f(xh));
      *(unsigned short*)(lds + L_AH + bx * ASTR + xwr + d * 2) = xh;
      *(unsigned short*)(lds + L_AL + bx * ASTR + xwr + d * 2) = xl;
    }
    __syncthreads();  // the ONLY barrier per step

    // ---- Phase B: G1 = [h1(t)|h2(t-1)] @ B1 ----
    // h1 fragments load directly into the carry registers (next phase A input)
#pragma unroll
    for (int ks = 0; ks < 2; ++ks) {
      int off = mcol * ASTR + h1s + ks * 64 + q * 16;
      ah1h[ks] = *(const s16x8*)(lds + L_AH + off);
      ah1l[ks] = *(const s16x8*)(lds + L_AL + off);
    }
    s16x8 h2h[2], h2l[2];
#pragma unroll
    for (int ks = 0; ks < 2; ++ks) {
      int off = mcol * ASTR + h2rd + ks * 64 + q * 16;
      h2h[ks] = *(const s16x8*)(lds + L_AH + off);
      h2l[ks] = *(const s16x8*)(lds + L_AL + off);
    }
    acc[0] = acc[1] = acc[2] = acc[3] = bias1r;
#pragma unroll
    for (int ks = 0; ks < 2; ++ks) {
      acc = mfma16(ah1h[ks], b1h[ks], acc);
      acc = mfma16(ah1l[ks], b1h[ks], acc);
      acc = mfma16(ah1h[ks], b1l[ks], acc);
    }
#pragma unroll
    for (int ks = 0; ks < 2; ++ks) {
      acc = mfma16(h2h[ks], b1h[ks + 2], acc);
      acc = mfma16(h2l[ks], b1h[ks + 2], acc);
      acc = mfma16(h2h[ks], b1l[ks + 2], acc);
    }
    // ---- Cell 2 ----
    {
      float g4[4] = {acc[0], acc[1], acc[2], acc[3]};
      quad_transpose(g4, lodd, l2b);
      float gi = sig_s(g4[0]), gf = sig_s(g4[1]);
      float gg = tanh_s(g4[2]), go = sig_s(g4[3]);
      c2 = fmaf(gf, c2, gi * gg);
      float h = go * tanh_c(c2);
      h2f = h;
      unsigned short hh = f2bf(h);
      int off = brow * ASTR + h2wr + kc * 2;
      *(unsigned short*)(lds + L_AH + off) = hh;
      *(unsigned short*)(lds + L_AL + off) = f2bf(h - bf2f(hh));
    }
    // no trailing barrier: all cross-step hazards separated by the next
    // step's barrier (x/h1/h2 parity double-buffered; h1(t) also in regs)
  };

#pragma unroll 1
  for (int tp = 0; tp < SEQL / 2; ++tp) {
    step(2 * tp, 0);
    step(2 * tp + 1, 1);
  }

  // ---- Head: f = relu(h2 @ W1.T + b1); out = f @ W2.T + b2 ----
  __syncthreads();
  *(float*)(lds + L_HD + brow * HDSTR + kc * 4) = h2f;
  __syncthreads();
  if (tid < 256) {
    const int s = tid & 15, bo = tid >> 4;
    const float* h2row = (const float*)(lds + L_HD + bo * HDSTR);
    float partial = 0.f;
#pragma unroll
    for (int kk4 = 0; kk4 < 4; ++kk4) {
      int kk = s * 4 + kk4;
      float f = b1[kk];
#pragma unroll
      for (int j = 0; j < 64; j += 4) {
        f32x4 w = *(const f32x4*)(W1 + kk * 64 + j);
        f = fmaf(w[0], h2row[j], f);
        f = fmaf(w[1], h2row[j + 1], f);
        f = fmaf(w[2], h2row[j + 2], f);
        f = fmaf(w[3], h2row[j + 3], f);
      }
      f = fmaxf(f, 0.f);
      partial = fmaf(f, W2[kk], partial);
    }
    partial += __shfl_xor(partial, 8, 64);
    partial += __shfl_xor(partial, 4, 64);
    partial += __shfl_xor(partial, 2, 64);
    partial += __shfl_xor(partial, 1, 64);
    if (s == 0) out[blockIdx.x * 16 + bo] = partial + b2[0];
  }
}

extern "C" void kernel_launch(void* const* d_in, const int* in_sizes, int n_in,
                              void* d_out, int out_size, void* d_ws, size_t ws_size,
                              hipStream_t stream) {
  const float* x    = (const float*)d_in[0];
  const float* Wih0 = (const float*)d_in[1];
  const float* Whh0 = (const float*)d_in[2];
  const float* bih0 = (const float*)d_in[3];
  const float* bhh0 = (const float*)d_in[4];
  const float* Wih1 = (const float*)d_in[5];
  const float* Whh1 = (const float*)d_in[6];
  const float* bih1 = (const float*)d_in[7];
  const float* bhh1 = (const float*)d_in[8];
  const float* W1   = (const float*)d_in[9];
  const float* b1   = (const float*)d_in[10];
  const float* W2   = (const float*)d_in[11];
  const float* b2   = (const float*)d_in[12];
  unsigned char* ws = (unsigned char*)d_ws;
  float* out = (float*)d_out;

  prep<<<(57856 + 255) / 256, 256, 0, stream>>>(Wih0, Whh0, bih0, bhh0,
                                                Wih1, Whh1, bih1, bhh1, ws);
  lstm_mfma4<<<256, 1024, 0, stream>>>(x, ws, W1, b1, W2, b2, out);
}

// Round 7
// 479.522 us; speedup vs baseline: 9.7916x; 1.0920x over previous
//
#include <hip/hip_runtime.h>
#include <cstdint>

typedef __attribute__((ext_vector_type(8))) _Float16 f16x8;
typedef __attribute__((ext_vector_type(4))) float f32x4;

#define SEQL 256

// ws byte offsets (prep output; same sizes as bf16 version, f16 encoding)
#define WS_B0H   0        // [3 kstep][16 ntile][64 lane][8] f16 = 49152 B
#define WS_B0L   49152    // lo pre-scaled x2048
#define WS_B1H   98304    // [4][16][64][8] f16 hi = 65536 B, then lo contiguous
#define WS_BIAS0 229376   // 256 f32, col-indexed (col = k*4+g), pre-scaled
#define WS_BIAS1 230400

// LDS: single f16 A buffer. Row = 656 B = 164 words (residue 4 mod 32:
// groups of 8 consecutive-mcol lanes tile all 32 banks -> b128 conflict-free).
// byte offs in row: x0@0(64B) x1@64 h1_0@128(128B) h1_1@256 h2_0@384 h2_1@512 pad@640
#define ASTR 656
#define L_A  0            // 16 x 656 = 10496
#define L_HD 10496        // head exchange: 16 rows x 272 B
#define HDSTR 272
#define LDS_TOTAL 14848

#define NEG_L   -1.4426950408889634f   // -log2(e)
#define NEG_2L  -2.8853900817779268f   // -2*log2(e)
#define LO_SCALE 2048.0f
#define LO_INV   4.8828125e-4f         // 1/2048

__device__ __forceinline__ float ex2(float x) { return __builtin_amdgcn_exp2f(x); }
__device__ __forceinline__ float rcp_(float x) { return __builtin_amdgcn_rcpf(x); }
__device__ __forceinline__ float sig_s(float vs) { return rcp_(1.f + ex2(vs)); }
__device__ __forceinline__ float tanh_s(float vs) {
  float e = ex2(-fabsf(vs));
  float r = (1.f - e) * rcp_(1.f + e);
  return copysignf(r, -vs);
}
__device__ __forceinline__ float tanh_c(float c) {
  float e = ex2(fabsf(c) * NEG_2L);
  float r = (1.f - e) * rcp_(1.f + e);
  return copysignf(r, c);
}
__device__ __forceinline__ f32x4 mfma16(f16x8 a, f16x8 b, f32x4 c) {
  return __builtin_amdgcn_mfma_f32_16x16x32_f16(a, b, c, 0, 0, 0);
}
__device__ __forceinline__ f16x8 zero8() {
  f16x8 z;
#pragma unroll
  for (int i = 0; i < 8; ++i) z[i] = (_Float16)0.f;
  return z;
}
template <int PAT>
__device__ __forceinline__ int dppq(int v) {
  return __builtin_amdgcn_update_dpp(v, v, PAT, 0xf, 0xf, true);
}
// 4x4 transpose across quad lanes x 4 regs. In: v[r]=M[row r][lane&3].
// Out: v[i]=M[lane&3][i].  (validated rounds 5-6)
__device__ __forceinline__ void quad_transpose(float (&v)[4], bool lodd, bool l2b) {
  int a0 = __float_as_int(v[0]), a1 = __float_as_int(v[1]);
  int a2 = __float_as_int(v[2]), a3 = __float_as_int(v[3]);
  int d0 = dppq<0xB1>(a0), d1 = dppq<0xB1>(a1);
  int d2 = dppq<0xB1>(a2), d3 = dppq<0xB1>(a3);
  int x0 = lodd ? d1 : a0;
  int x1 = lodd ? a1 : d0;
  int x2 = lodd ? d3 : a2;
  int x3 = lodd ? a3 : d2;
  int e0 = dppq<0x4E>(x0), e1 = dppq<0x4E>(x1);
  int e2 = dppq<0x4E>(x2), e3 = dppq<0x4E>(x3);
  v[0] = __int_as_float(l2b ? e2 : x0);
  v[1] = __int_as_float(l2b ? e3 : x1);
  v[2] = __int_as_float(l2b ? x2 : e0);
  v[3] = __int_as_float(l2b ? x3 : e1);
}

// Pack weights into MFMA B-fragment order, f16 hi + f16 lo(x2048) split,
// pre-scaled by -log2e (i,f,o) / -2log2e (g). Layout identical to prior rounds.
__global__ __launch_bounds__(256) void prep(
    const float* __restrict__ Wih0, const float* __restrict__ Whh0,
    const float* __restrict__ bih0, const float* __restrict__ bhh0,
    const float* __restrict__ Wih1, const float* __restrict__ Whh1,
    const float* __restrict__ bih1, const float* __restrict__ bhh1,
    unsigned char* __restrict__ ws) {
  int e = blockIdx.x * 256 + threadIdx.x;
  if (e < 24576) {  // B0: K=96 = [x(32)|h1(64)]
    int j = e & 7, lane = (e >> 3) & 63, nt = (e >> 9) & 15, ks = e >> 13;
    int kdim = ks * 32 + (lane >> 4) * 8 + j;
    int col = nt * 16 + (lane & 15);
    int ko = col >> 2, g = col & 3;
    float w = (kdim < 32) ? Wih0[(g * 64 + ko) * 32 + kdim]
                          : Whh0[(g * 64 + ko) * 64 + (kdim - 32)];
    w *= (g == 2) ? NEG_2L : NEG_L;
    _Float16 hi = (_Float16)w;
    _Float16 lo = (_Float16)((w - (float)hi) * LO_SCALE);
    ((_Float16*)(ws + WS_B0H))[e] = hi;
    ((_Float16*)(ws + WS_B0L))[e] = lo;
  } else if (e < 57344) {  // B1: K=128 = [h1(64)|h2(64)]
    int r = e - 24576;
    int j = r & 7, lane = (r >> 3) & 63, nt = (r >> 9) & 15, ks = r >> 13;
    int kdim = ks * 32 + (lane >> 4) * 8 + j;
    int col = nt * 16 + (lane & 15);
    int ko = col >> 2, g = col & 3;
    float w = (kdim < 64) ? Wih1[(g * 64 + ko) * 64 + kdim]
                          : Whh1[(g * 64 + ko) * 64 + (kdim - 64)];
    w *= (g == 2) ? NEG_2L : NEG_L;
    _Float16 hi = (_Float16)w;
    _Float16 lo = (_Float16)((w - (float)hi) * LO_SCALE);
    ((_Float16*)(ws + WS_B1H))[r] = hi;
    ((_Float16*)(ws + WS_B1H + 65536))[r] = lo;
  } else if (e < 57856) {  // biases (pre-scaled, fp32)
    int r = e - 57344;
    int col = r & 255, ko = col >> 2, g = col & 3;
    float v = (r < 256) ? bih0[g * 64 + ko] + bhh0[g * 64 + ko]
                        : bih1[g * 64 + ko] + bhh1[g * 64 + ko];
    v *= (g == 2) ? NEG_2L : NEG_L;
    ((float*)(ws + (r < 256 ? WS_BIAS0 : WS_BIAS1)))[col] = v;
  }
}

__global__ __launch_bounds__(1024, 4) void lstm_mfma5(
    const float* __restrict__ x, const unsigned char* __restrict__ ws,
    const float* __restrict__ W1, const float* __restrict__ b1,
    const float* __restrict__ W2, const float* __restrict__ b2,
    float* __restrict__ out) {
  __shared__ __align__(16) unsigned char lds[LDS_TOTAL];
  const int tid = threadIdx.x;
  const int lane = tid & 63, wave = tid >> 6;  // 16 waves, 1 ntile each
  const int q = lane >> 4, mcol = lane & 15;
  const bool lodd = (lane & 1) != 0, l2b = (lane & 2) != 0;

  // ---- Weight fragments -> registers (loop-invariant, 1 ntile/wave) ----
  f16x8 b0h[3], b0l[3], b1h[4], b1l[4];
#pragma unroll
  for (int ks = 0; ks < 3; ++ks) {
    int rec = (ks * 16 + wave) * 64 + lane;
    b0h[ks] = ((const f16x8*)(ws + WS_B0H))[rec];
    b0l[ks] = ((const f16x8*)(ws + WS_B0L))[rec];
  }
#pragma unroll
  for (int ks = 0; ks < 4; ++ks) {
    int rec = (ks * 16 + wave) * 64 + lane;
    b1h[ks] = ((const f16x8*)(ws + WS_B1H))[rec];
    b1l[ks] = ((const f16x8*)(ws + WS_B1H + 65536))[rec];
  }
  const int col = wave * 16 + mcol;
  const float bias0r = ((const float*)(ws + WS_BIAS0))[col];
  const float bias1r = ((const float*)(ws + WS_BIAS1))[col];

  // Zero A buffer (10496 B = 2624 words)
  for (int i = tid; i < 2624; i += 1024) ((unsigned*)(lds + L_A))[i] = 0u;

  // x staging role (threads 0..511): bx = tid>>5 (0..15), d = tid&31
  const bool do_x = tid < 512;
  const int bx = tid >> 5, d = tid & 31;
  const float* xcol = x + (size_t)(blockIdx.x * 16 + (do_x ? bx : 0)) * (SEQL * 32) + d;
  if (do_x) {
    *(_Float16*)(lds + L_A + bx * ASTR + d * 2) = (_Float16)xcol[0];  // x(0)
  }
  // cell role: 1 cell/layer: (brow = q*4+(lane&3), kc = wave*4+(mcol>>2))
  const int brow = q * 4 + (lane & 3);
  const int kc = wave * 4 + (mcol >> 2);
  float c1 = 0.f, c2 = 0.f, h2f = 0.f;
  f16x8 ah1[2];  // h1(t-1) A-fragments carried in registers
  ah1[0] = ah1[1] = zero8();
  __syncthreads();

  auto step = [&](int t, const int par) {
    const int xrd = par * 64, xwr = (par ^ 1) * 64;
    const int h1s = 128 + par * 128;          // h1(t) slot
    const int h2rd = 384 + (par ^ 1) * 128;   // h2(t-1)
    const int h2wr = 384 + par * 128;         // h2(t)

    float xnext = 0.f;
    if (do_x && t < SEQL - 1) xnext = xcol[(t + 1) * 32];

    // ---- Phase A: G0 = [x(t)|h1(t-1)] @ (B0h + B0l/2048) ----
    f16x8 ax = *(const f16x8*)(lds + L_A + mcol * ASTR + xrd + q * 16);
    f32x4 accH, accL;
    accH[0] = accH[1] = accH[2] = accH[3] = bias0r;
    accL[0] = accL[1] = accL[2] = accL[3] = 0.f;
    accH = mfma16(ax, b0h[0], accH);
    accL = mfma16(ax, b0l[0], accL);
#pragma unroll
    for (int ks = 0; ks < 2; ++ks) {
      accH = mfma16(ah1[ks], b0h[ks + 1], accH);
      accL = mfma16(ah1[ks], b0l[ks + 1], accL);
    }
    // ---- Cell 1 (in-register gate transpose) ----
    {
      float g4[4];
#pragma unroll
      for (int i = 0; i < 4; ++i) g4[i] = fmaf(accL[i], LO_INV, accH[i]);
      quad_transpose(g4, lodd, l2b);
      float gi = sig_s(g4[0]), gf = sig_s(g4[1]);
      float gg = tanh_s(g4[2]), go = sig_s(g4[3]);
      c1 = fmaf(gf, c1, gi * gg);
      float h = go * tanh_c(c1);
      *(_Float16*)(lds + L_A + brow * ASTR + h1s + kc * 2) = (_Float16)h;
    }
    if (do_x && t < SEQL - 1) {
      *(_Float16*)(lds + L_A + bx * ASTR + xwr + d * 2) = (_Float16)xnext;
    }
    __syncthreads();  // the ONLY barrier per step

    // ---- Phase B: G1 = [h1(t)|h2(t-1)] @ (B1h + B1l/2048) ----
    // h1 fragments load directly into carry registers (next phase A input)
#pragma unroll
    for (int ks = 0; ks < 2; ++ks)
      ah1[ks] = *(const f16x8*)(lds + L_A + mcol * ASTR + h1s + ks * 64 + q * 16);
    f16x8 h2fr[2];
#pragma unroll
    for (int ks = 0; ks < 2; ++ks)
      h2fr[ks] = *(const f16x8*)(lds + L_A + mcol * ASTR + h2rd + ks * 64 + q * 16);
    accH[0] = accH[1] = accH[2] = accH[3] = bias1r;
    accL[0] = accL[1] = accL[2] = accL[3] = 0.f;
#pragma unroll
    for (int ks = 0; ks < 2; ++ks) {
      accH = mfma16(ah1[ks], b1h[ks], accH);
      accL = mfma16(ah1[ks], b1l[ks], accL);
    }
#pragma unroll
    for (int ks = 0; ks < 2; ++ks) {
      accH = mfma16(h2fr[ks], b1h[ks + 2], accH);
      accL = mfma16(h2fr[ks], b1l[ks + 2], accL);
    }
    // ---- Cell 2 ----
    {
      float g4[4];
#pragma unroll
      for (int i = 0; i < 4; ++i) g4[i] = fmaf(accL[i], LO_INV, accH[i]);
      quad_transpose(g4, lodd, l2b);
      float gi = sig_s(g4[0]), gf = sig_s(g4[1]);
      float gg = tanh_s(g4[2]), go = sig_s(g4[3]);
      c2 = fmaf(gf, c2, gi * gg);
      float h = go * tanh_c(c2);
      h2f = h;
      *(_Float16*)(lds + L_A + brow * ASTR + h2wr + kc * 2) = (_Float16)h;
    }
    // no trailing barrier: cross-step hazards separated by next step's
    // barrier (x/h1/h2 parity double-buffered; h1(t) also carried in regs)
  };

#pragma unroll 1
  for (int tp = 0; tp < SEQL / 2; ++tp) {
    step(2 * tp, 0);
    step(2 * tp + 1, 1);
  }

  // ---- Head: f = relu(h2 @ W1.T + b1); out = f @ W2.T + b2 (fp32 h2) ----
  __syncthreads();
  *(float*)(lds + L_HD + brow * HDSTR + kc * 4) = h2f;
  __syncthreads();
  if (tid < 256) {
    const int s = tid & 15, bo = tid >> 4;
    const float* h2row = (const float*)(lds + L_HD + bo * HDSTR);
    float partial = 0.f;
#pragma unroll
    for (int kk4 = 0; kk4 < 4; ++kk4) {
      int kk = s * 4 + kk4;
      float f = b1[kk];
#pragma unroll
      for (int j = 0; j < 64; j += 4) {
        f32x4 w = *(const f32x4*)(W1 + kk * 64 + j);
        f = fmaf(w[0], h2row[j], f);
        f = fmaf(w[1], h2row[j + 1], f);
        f = fmaf(w[2], h2row[j + 2], f);
        f = fmaf(w[3], h2row[j + 3], f);
      }
      f = fmaxf(f, 0.f);
      partial = fmaf(f, W2[kk], partial);
    }
    partial += __shfl_xor(partial, 8, 64);
    partial += __shfl_xor(partial, 4, 64);
    partial += __shfl_xor(partial, 2, 64);
    partial += __shfl_xor(partial, 1, 64);
    if (s == 0) out[blockIdx.x * 16 + bo] = partial + b2[0];
  }
}

extern "C" void kernel_launch(void* const* d_in, const int* in_sizes, int n_in,
                              void* d_out, int out_size, void* d_ws, size_t ws_size,
                              hipStream_t stream) {
  const float* x    = (const float*)d_in[0];
  const float* Wih0 = (const float*)d_in[1];
  const float* Whh0 = (const float*)d_in[2];
  const float* bih0 = (const float*)d_in[3];
  const float* bhh0 = (const float*)d_in[4];
  const float* Wih1 = (const float*)d_in[5];
  const float* Whh1 = (const float*)d_in[6];
  const float* bih1 = (const float*)d_in[7];
  const float* bhh1 = (const float*)d_in[8];
  const float* W1   = (const float*)d_in[9];
  const float* b1   = (const float*)d_in[10];
  const float* W2   = (const float*)d_in[11];
  const float* b2   = (const float*)d_in[12];
  unsigned char* ws = (unsigned char*)d_ws;
  float* out = (float*)d_out;

  prep<<<(57856 + 255) / 256, 256, 0, stream>>>(Wih0, Whh0, bih0, bhh0,
                                                Wih1, Whh1, bih1, bhh1, ws);
  lstm_mfma5<<<256, 1024, 0, stream>>>(x, ws, W1, b1, W2, b2, out);
}